// Round 14
// baseline (279.744 us; speedup 1.0000x reference)
//
#include <hip/hip_runtime.h>
#include <math.h>

// B=16, L=64, H=512, N_LABELS=64, ITERS=3
// Round-27: round-13 base (276.2us). hid + sfbuf stored as bf16 (they feed
// only tanh->fp8-QK; bf16 error 0.4% << fp8's 3%): k_score per-block L2
// stream 388->324KB, prep loads halve, k_lin/k_lin1 C-store traffic halves.
// r_slot / fp chain stay f32-exact.
//
// ws layout (float offsets):
//   wbp 0 [131072] W_ID fp8 (256KB, repacked); fp at 131072 [131072]
//   v1h 393216 [131072] bf16 V1 (hi only)
//   sfbuf 655360 (bf16, 1MB), r_slot 1179648 (f32), hid 1703936 (bf16, 1MB)
//   smat 2228224 [4096]
//   wia_t 2240512, wsa_t 2306048 [65536 each]
//   wsf_t 2371584, vsf_t 2633728 [262144 each]

typedef __attribute__((ext_vector_type(8))) short bf16x8;
typedef __attribute__((ext_vector_type(4))) float f32x4;
typedef long i64fr;
typedef __attribute__((ext_vector_type(2))) long i64x2;

__device__ inline short f2bf(float x) {  // RNE
  unsigned u = __float_as_uint(x);
  unsigned r = (u + 0x7fffu + ((u >> 16) & 1u)) >> 16;
  return (short)r;
}
__device__ inline float bf2f(short s) {
  return __uint_as_float(((unsigned)(unsigned short)s) << 16);
}
__device__ inline unsigned char f2fp8(float x) {  // e4m3 RNE
  unsigned v = __builtin_amdgcn_cvt_pk_fp8_f32(x, x, 0, false);
  return (unsigned char)(v & 0xffu);
}
__device__ inline float ftanh(float x) {
  float t = __expf(2.f * x);
  return 1.f - 2.f * __builtin_amdgcn_rcpf(t + 1.f);
}
__device__ inline bf16x8 pack8hi(float4 a, float4 b) {
  bf16x8 h;
  h[0] = f2bf(a.x); h[1] = f2bf(a.y); h[2] = f2bf(a.z); h[3] = f2bf(a.w);
  h[4] = f2bf(b.x); h[5] = f2bf(b.y); h[6] = f2bf(b.z); h[7] = f2bf(b.w);
  return h;
}

// ---- first linear + all prep + fused first-iteration mid (fp planes) ----
__global__ __launch_bounds__(256) void k_lin1(
    const float* __restrict__ A, const float* __restrict__ rawB,
    const float* __restrict__ bias, short* __restrict__ C,
    const float* __restrict__ W_ID, const float* __restrict__ V1,
    const float* __restrict__ W_ia, const float* __restrict__ W_sa,
    const float* __restrict__ W_SF, const float* __restrict__ V_SF,
    const float* __restrict__ c_inte, const float* __restrict__ c_slot,
    unsigned char* __restrict__ wbp, short* __restrict__ v1h,
    float* __restrict__ wia_t, float* __restrict__ wsa_t,
    float* __restrict__ wsf_t, float* __restrict__ vsf_t,
    float* __restrict__ fp) {
  __shared__ short Ah[2][512];
  __shared__ float tile[64][65];
  __shared__ float riv2[512], red2[256], tm2[64], ts2[64];
  const int nh = blockIdx.y;
  const int t = threadIdx.x;

  if (nh >= 4) {
    const int pid = (nh - 4) * 64 + blockIdx.x;
    if (pid < 256) {  // wbp pack (fp8) layout [ks][w][lane][c][e]
#pragma unroll
      for (int e4 = 0; e4 < 4; ++e4) {
        int idx = pid * 1024 + e4 * 256 + t;
        int e = idx & 7, c = (idx >> 3) & 3;
        int lane = (idx >> 5) & 63, w8 = (idx >> 11) & 7;
        int ks = idx >> 14;
        int g = (w8 * 4 + c) * 16 + (lane & 15);
        int h = ks * 32 + (lane >> 4) * 8 + e;
        wbp[idx] = f2fp8(W_ID[g * 512 + h]);
      }
    } else if (pid < 512) {  // v1 pack (bf16 hi only)
      int p = pid - 256;
#pragma unroll
      for (int e = 0; e < 4; ++e) {
        int idx = p * 1024 + e * 256 + t;
        int j = idx & 7, lane = (idx >> 3) & 63;
        int ntile = (idx >> 9) & 31, kstep = idx >> 14;
        int g = ntile * 16 + (lane & 15);
        int h = kstep * 32 + (lane >> 4) * 8 + j;
        v1h[idx] = f2bf(V1[g * 512 + h]);
      }
    } else if (pid < 672) {  // transposes
      int p = pid - 512;
      const float* tin;
      float* tout;
      int R, C2, c0, r0;
      if (p < 64) {
        tin = W_SF; tout = wsf_t; R = 512; C2 = 512;
        c0 = (p & 7) * 64; r0 = (p >> 3) * 64;
      } else if (p < 128) {
        int q = p - 64;
        tin = V_SF; tout = vsf_t; R = 512; C2 = 512;
        c0 = (q & 7) * 64; r0 = (q >> 3) * 64;
      } else if (p < 144) {
        tin = W_ia; tout = wia_t; R = 64; C2 = 1024;
        c0 = (p - 128) * 64; r0 = 0;
      } else {
        tin = W_sa; tout = wsa_t; R = 64; C2 = 1024;
        c0 = (p - 144) * 64; r0 = 0;
      }
      const int tx = t & 63, ty = t >> 6;
#pragma unroll
      for (int it2 = 0; it2 < 16; ++it2) {
        int rl = ty + it2 * 4;
        tile[rl][tx] = tin[(r0 + rl) * C2 + c0 + tx];
      }
      __syncthreads();
#pragma unroll
      for (int it2 = 0; it2 < 16; ++it2) {
        int cl = ty + it2 * 4;
        tout[(c0 + cl) * R + r0 + tx] = tile[tx][cl];
      }
    } else if (pid < 800) {  // fused first-mid: one (b,hc) chunk each (nch=8)
      const int q = pid - 672;
      const int b = q >> 3, hc = q & 7;
      const int hl = t & 63, kq = t >> 6;  // kq in 0..3
      riv2[t] = c_inte[b * 512 + t];
      riv2[t + 256] = c_inte[b * 512 + 256 + t];
      __syncthreads();
      {  // tm[hl] = sum_k riv[k] * W_SF[hc*64+hl][k]
        const float* wrow = W_SF + (hc * 64 + hl) * 512 + kq * 128;
        float p = 0.f;
#pragma unroll 8
        for (int k = 0; k < 128; k += 4) {
          float4 wv = *(const float4*)(wrow + k);
          p += wv.x * riv2[kq * 128 + k] + wv.y * riv2[kq * 128 + k + 1] +
               wv.z * riv2[kq * 128 + k + 2] + wv.w * riv2[kq * 128 + k + 3];
        }
        red2[t] = p;
      }
      __syncthreads();
      if (t < 64) tm2[t] = red2[t] + red2[t + 64] + red2[t + 128] + red2[t + 192];
      __syncthreads();
      {  // ts[hl] = sum_l tanh(c_slot[b,l,hc*64+hl] + tm[hl])
        float tmph = tm2[hl];
        const float* cp = c_slot + (b * 64 + kq * 16) * 512 + hc * 64 + hl;
        float s = 0.f;
#pragma unroll
        for (int l = 0; l < 16; ++l) s += ftanh(cp[l * 512] + tmph);
        red2[t] = s;
      }
      __syncthreads();
      if (t < 64) ts2[t] = red2[t] + red2[t + 64] + red2[t + 128] + red2[t + 192];
      __syncthreads();
      {  // fp[(b*8+hc)*512 + to] = sum_k ts[k] * V_SF[to][hc*64+k]
#pragma unroll
        for (int half = 0; half < 2; ++half) {
          int to = t + half * 256;
          const float* vrow = V_SF + to * 512 + hc * 64;
          float p = 0.f;
#pragma unroll 8
          for (int k = 0; k < 64; k += 4) {
            float4 vv = *(const float4*)(vrow + k);
            p += vv.x * ts2[k] + vv.y * ts2[k + 1] + vv.z * ts2[k + 2] +
                 vv.w * ts2[k + 3];
          }
          fp[(b * 8 + hc) * 512 + to] = p;
        }
      }
    }
    return;
  }

  // ---- gemm planes (nh<4): raw f32 B, bf16-hi only; bf16 C out ----
  const int m0 = blockIdx.x * 16;
  const int w = t >> 6, lane = t & 63;
  const int lq = lane >> 4, lm = lane & 15;
  f32x4 acc[2];
#pragma unroll
  for (int c = 0; c < 2; ++c) acc[c] = (f32x4){0.f, 0.f, 0.f, 0.f};

  const int nt0 = nh * 8 + w * 2;
  const float* vb0 = rawB + (nt0 * 16 + lm) * 512 + lq * 8;
  const float* vb1 = vb0 + 16 * 512;

  const int la = t >> 2, j0 = (t & 3) * 2;
  const int m = la & 15, kk = (la >> 4) * 8 + j0;
  const float* abase = A + (m0 + m) * 512 + kk;
  float2 x = *(const float2*)abase;

  for (int ks = 0; ks < 16; ++ks) {
    const int buf = ks & 1;
    float4 q0 = *(const float4*)(vb0 + ks * 32);
    float4 q1 = *(const float4*)(vb0 + ks * 32 + 4);
    float4 p0 = *(const float4*)(vb1 + ks * 32);
    float4 p1 = *(const float4*)(vb1 + ks * 32 + 4);
    float2 xn = x;
    if (ks < 15) xn = *(const float2*)(abase + (ks + 1) * 32);
    *(short2*)&Ah[buf][t * 2] = make_short2(f2bf(x.x), f2bf(x.y));
    bf16x8 b0h = pack8hi(q0, q1);
    bf16x8 b1h = pack8hi(p0, p1);
    __syncthreads();
    bf16x8 ah = *(const bf16x8*)&Ah[buf][lane * 8];
    acc[0] = __builtin_amdgcn_mfma_f32_16x16x32_bf16(ah, b0h, acc[0], 0, 0, 0);
    acc[1] = __builtin_amdgcn_mfma_f32_16x16x32_bf16(ah, b1h, acc[1], 0, 0, 0);
    x = xn;
  }
#pragma unroll
  for (int c = 0; c < 2; ++c)
#pragma unroll
    for (int reg = 0; reg < 4; ++reg) {
      int mm = m0 + lq * 4 + reg;
      int n = (nt0 + c) * 16 + lm;
      C[mm * 512 + n] = f2bf(acc[c][reg] + bias[n]);
    }
}

// ---- bf16 MFMA linear; fl = sum of nch fp partials; bf16 C out ----
// grid (64, 4); A = f[b,:] (x) c_slot, nh==0 writes r_slot (f32), zeroes smat.
__global__ __launch_bounds__(256) void k_lin(const float* __restrict__ c_slot,
                                             const float* __restrict__ fp,
                                             int nch,
                                             const short* __restrict__ bh,
                                             short* __restrict__ C,
                                             float* __restrict__ rs_out,
                                             float* __restrict__ smat0) {
  __shared__ short Ah[2][512];
  __shared__ float fl[512];
  const int m0 = blockIdx.x * 16;
  const int nh = blockIdx.y;
  const int t = threadIdx.x;
  if (nh == 0 && blockIdx.x < 8) {
    smat0[blockIdx.x * 512 + t] = 0.f;
    smat0[blockIdx.x * 512 + 256 + t] = 0.f;
  }
  {
    const float* fb = fp + (blockIdx.x >> 2) * nch * 512;
    float s0 = 0.f, s1 = 0.f;
    for (int hc = 0; hc < nch; ++hc) {
      s0 += fb[hc * 512 + t];
      s1 += fb[hc * 512 + 256 + t];
    }
    fl[t] = s0;
    fl[t + 256] = s1;
  }
  const int w = t >> 6, lane = t & 63;
  const int lq = lane >> 4, lm = lane & 15;
  f32x4 acc[2];
#pragma unroll
  for (int c = 0; c < 2; ++c) acc[c] = (f32x4){0.f, 0.f, 0.f, 0.f};

  const bf16x8* gbh = (const bf16x8*)bh + (nh * 8 + w * 2) * 64 + lane;

  const int la = t >> 2, j0 = (t & 3) * 2;
  const int m = la & 15, kk = (la >> 4) * 8 + j0;
  const float* abase = c_slot + (m0 + m) * 512 + kk;
  float* rbase = rs_out + (m0 + m) * 512 + kk;
  __syncthreads();  // fl ready
  float2 x = *(const float2*)abase;

  for (int ks = 0; ks < 16; ++ks) {
    const int buf = ks & 1;
    bf16x8 b0h = gbh[ks * 2048];
    bf16x8 b1h = gbh[ks * 2048 + 64];
    float2 xn = x;
    if (ks < 15) xn = *(const float2*)(abase + (ks + 1) * 32);
    float a0 = x.x * fl[ks * 32 + kk];
    float a1 = x.y * fl[ks * 32 + kk + 1];
    if (nh == 0) *(float2*)(rbase + ks * 32) = make_float2(a0, a1);
    *(short2*)&Ah[buf][t * 2] = make_short2(f2bf(a0), f2bf(a1));
    __syncthreads();
    bf16x8 ah = *(const bf16x8*)&Ah[buf][lane * 8];
    acc[0] = __builtin_amdgcn_mfma_f32_16x16x32_bf16(ah, b0h, acc[0], 0, 0, 0);
    acc[1] = __builtin_amdgcn_mfma_f32_16x16x32_bf16(ah, b1h, acc[1], 0, 0, 0);
    x = xn;
  }
#pragma unroll
  for (int c = 0; c < 2; ++c)
#pragma unroll
    for (int reg = 0; reg < 4; ++reg) {
      int mm = m0 + lq * 4 + reg;
      int n = nh * 128 + (w * 2 + c) * 16 + lm;
      C[mm * 512 + n] = f2bf(acc[c][reg]);
    }
}

// ---- per-iteration mid chain (it=1,2): 256 blocks = (b:16) x (hcc:16) ----
// Writes partials fp[(b*16+hcc)*512 + :] (no atomics, no pre-zeroing).
__global__ __launch_bounds__(512) void k_mid(const float* __restrict__ smat,
                                             const float* __restrict__ r_slot,
                                             const float* __restrict__ c_inte,
                                             const float* __restrict__ c_slot,
                                             const float* __restrict__ wsf_t,
                                             const float* __restrict__ vsf_t,
                                             float* __restrict__ fp) {
  __shared__ float av[64];
  __shared__ float riv[512];
  __shared__ float red[512];
  __shared__ float tm[32], ts[32];
  const int b = blockIdx.x >> 4, hcc = blockIdx.x & 15;
  const int t = threadIdx.x;

  if (t < 256) {
    int w = t >> 6, lane = t & 63;
    for (int r = w * 16; r < w * 16 + 16; ++r) {
      float v = smat[r * 64 + lane];
      float s = v;
      s += __shfl_xor(s, 1);
      s += __shfl_xor(s, 2);
      s += __shfl_xor(s, 4);
      s += __shfl_xor(s, 8);
      s += __shfl_xor(s, 16);
      s += __shfl_xor(s, 32);
      float d = __shfl(v, r);
      if (lane == 0) av[r] = d / s;
    }
  }
  __syncthreads();
  {
    float a = 0.f;
    const float* rp = r_slot + b * 64 * 512 + t;
#pragma unroll 8
    for (int i = 0; i < 64; ++i) a += av[i] * rp[i * 512];
    riv[t] = a + c_inte[b * 512 + t];
  }
  __syncthreads();
  const int hl2 = t & 31, kq2 = t >> 5;  // 16 k-groups of 32
  {
    const float* wp = wsf_t + hcc * 32 + hl2;
    float p = 0.f;
#pragma unroll 8
    for (int k = kq2 * 32; k < kq2 * 32 + 32; ++k) p += riv[k] * wp[k * 512];
    red[t] = p;
  }
  __syncthreads();
  if (t < 32) {
    float s = 0.f;
#pragma unroll
    for (int q = 0; q < 16; ++q) s += red[q * 32 + t];
    tm[t] = s;
  }
  __syncthreads();
  {
    float tmph = tm[hl2];
    const float* cp = c_slot + (b * 64 + kq2 * 4) * 512 + hcc * 32 + hl2;
    float s = 0.f;
#pragma unroll
    for (int l = 0; l < 4; ++l) s += ftanh(cp[l * 512] + tmph);
    red[t] = s;
  }
  __syncthreads();
  if (t < 32) {
    float s = 0.f;
#pragma unroll
    for (int q = 0; q < 16; ++q) s += red[q * 32 + t];
    ts[t] = s;
  }
  __syncthreads();
  {
    const float* vp = vsf_t + (hcc * 32) * 512 + t;
    float p = 0.f;
#pragma unroll 8
    for (int k = 0; k < 32; ++k) p += ts[k] * vp[k * 512];
    fp[blockIdx.x * 512 + t] = p;
  }
}

// ---- dominant kernel v8-fp8: bf16 hid/sf inputs, contiguous B frags ----
__global__ __launch_bounds__(512, 4) void k_score(
    const short* __restrict__ hid, const short* __restrict__ sf,
    const unsigned char* __restrict__ wbp, float* __restrict__ smat,
    float* __restrict__ oz) {
  __shared__ unsigned char As[16][2048];  // 32 KB
  __shared__ float red[8][64];
  const int i = blockIdx.x, b = blockIdx.y;
  const int t = threadIdx.x;
  if (oz && i == 1 && b < 2) oz[b * 512 + t] = 0.f;
  const int w = t >> 6, lane = t & 63;
  const int lq = lane >> 4, lm = lane & 15;

  f32x4 acc[4][4];
#pragma unroll
  for (int r = 0; r < 4; ++r)
#pragma unroll
    for (int c = 0; c < 4; ++c) acc[r][c] = (f32x4){0.f, 0.f, 0.f, 0.f};

  const short* hrow = hid + (b * 64 + i) * 512;
  const short* sfb = sf + b * 64 * 512;

  const int fid = t >> 1, half = t & 1;
  const int am = (fid >> 6) * 16 + (fid & 15);
  const int ak = ((fid >> 4) & 3) * 8 + half * 4;
  const int aoff = fid * 8 + half * 4;  // byte offset within plane

  const short* hp0 = hrow + ak;
  const short* sp0 = sfb + am * 512 + ak;

  // wbp layout: [ks][w:8][lane:64][c:4][8B]; per lane 32B contiguous.
  const i64x2* gb = (const i64x2*)wbp + (w * 64 + lane) * 2;
  i64x2 nba = gb[0];      // c0,c1
  i64x2 nbb = gb[1];      // c2,c3

#pragma unroll 4
  for (int ks = 0; ks < 16; ++ks) {
    short4 hv = *(const short4*)(hp0 + ks * 32);
    short4 sv = *(const short4*)(sp0 + ks * 32);
    unsigned pk = __builtin_amdgcn_cvt_pk_fp8_f32(
        ftanh(bf2f(hv.x) + bf2f(sv.x)), ftanh(bf2f(hv.y) + bf2f(sv.y)),
        0, false);
    pk = __builtin_amdgcn_cvt_pk_fp8_f32(
        ftanh(bf2f(hv.z) + bf2f(sv.z)), ftanh(bf2f(hv.w) + bf2f(sv.w)),
        pk, true);
    *(unsigned*)&As[ks][aoff] = pk;
  }
  __syncthreads();

  for (int ks = 0; ks < 16; ++ks) {
    i64fr b0 = nba.x, b1 = nba.y, b2 = nbb.x, b3 = nbb.y;
    if (ks < 15) {
      nba = gb[(ks + 1) * 1024];
      nbb = gb[(ks + 1) * 1024 + 1];
    }
    i64fr af0 = *(const i64fr*)&As[ks][(0 * 64 + lane) * 8];
    i64fr af1 = *(const i64fr*)&As[ks][(1 * 64 + lane) * 8];
    i64fr af2 = *(const i64fr*)&As[ks][(2 * 64 + lane) * 8];
    i64fr af3 = *(const i64fr*)&As[ks][(3 * 64 + lane) * 8];
    acc[0][0] = __builtin_amdgcn_mfma_f32_16x16x32_fp8_fp8(af0, b0, acc[0][0], 0, 0, 0);
    acc[1][0] = __builtin_amdgcn_mfma_f32_16x16x32_fp8_fp8(af1, b0, acc[1][0], 0, 0, 0);
    acc[2][0] = __builtin_amdgcn_mfma_f32_16x16x32_fp8_fp8(af2, b0, acc[2][0], 0, 0, 0);
    acc[3][0] = __builtin_amdgcn_mfma_f32_16x16x32_fp8_fp8(af3, b0, acc[3][0], 0, 0, 0);
    acc[0][1] = __builtin_amdgcn_mfma_f32_16x16x32_fp8_fp8(af0, b1, acc[0][1], 0, 0, 0);
    acc[1][1] = __builtin_amdgcn_mfma_f32_16x16x32_fp8_fp8(af1, b1, acc[1][1], 0, 0, 0);
    acc[2][1] = __builtin_amdgcn_mfma_f32_16x16x32_fp8_fp8(af2, b1, acc[2][1], 0, 0, 0);
    acc[3][1] = __builtin_amdgcn_mfma_f32_16x16x32_fp8_fp8(af3, b1, acc[3][1], 0, 0, 0);
    acc[0][2] = __builtin_amdgcn_mfma_f32_16x16x32_fp8_fp8(af0, b2, acc[0][2], 0, 0, 0);
    acc[1][2] = __builtin_amdgcn_mfma_f32_16x16x32_fp8_fp8(af1, b2, acc[1][2], 0, 0, 0);
    acc[2][2] = __builtin_amdgcn_mfma_f32_16x16x32_fp8_fp8(af2, b2, acc[2][2], 0, 0, 0);
    acc[3][2] = __builtin_amdgcn_mfma_f32_16x16x32_fp8_fp8(af3, b2, acc[3][2], 0, 0, 0);
    acc[0][3] = __builtin_amdgcn_mfma_f32_16x16x32_fp8_fp8(af0, b3, acc[0][3], 0, 0, 0);
    acc[1][3] = __builtin_amdgcn_mfma_f32_16x16x32_fp8_fp8(af1, b3, acc[1][3], 0, 0, 0);
    acc[2][3] = __builtin_amdgcn_mfma_f32_16x16x32_fp8_fp8(af2, b3, acc[2][3], 0, 0, 0);
    acc[3][3] = __builtin_amdgcn_mfma_f32_16x16x32_fp8_fp8(af3, b3, acc[3][3], 0, 0, 0);
  }

#pragma unroll
  for (int r = 0; r < 4; ++r) {
#pragma unroll
    for (int reg = 0; reg < 4; ++reg) {
      float v = __expf(acc[r][0][reg]) + __expf(acc[r][1][reg]) +
                __expf(acc[r][2][reg]) + __expf(acc[r][3][reg]);
      v += __shfl_down(v, 8, 16);
      v += __shfl_down(v, 4, 16);
      v += __shfl_down(v, 2, 16);
      v += __shfl_down(v, 1, 16);
      if (lm == 0) red[w][r * 16 + lq * 4 + reg] = v;
    }
  }
  __syncthreads();
  if (t < 64) {
    float s = 0.f;
#pragma unroll
    for (int ww = 0; ww < 8; ++ww) s += red[ww][t];
    atomicAdd(&smat[i * 64 + t], s);
  }
}

// ---- post: k_slot (bx<256) + k_fin (bx>=256) merged (round-0 form) ----
__global__ __launch_bounds__(256) void k_post(const float* __restrict__ smat,
                                              const float* __restrict__ r_slot,
                                              const float* __restrict__ c_inte,
                                              const float* __restrict__ h,
                                              const float* __restrict__ wia_t,
                                              const float* __restrict__ wsa_t,
                                              float* __restrict__ out) {
  __shared__ float av[64], riv[64], red[256];
  const int t = threadIdx.x;
  if (blockIdx.x < 256) {
    int idx = blockIdx.x * 256 + t;  // 65536
    int ml = idx >> 6, n = idx & 63;
    const float* x1 = h + ml * 512;
    const float* x2 = r_slot + ml * 512;
    float acc = 0.f;
    for (int k = 0; k < 512; k += 4) {
      float4 x = *(const float4*)(x1 + k);
      acc += x.x * wsa_t[k * 64 + n] + x.y * wsa_t[(k + 1) * 64 + n] +
             x.z * wsa_t[(k + 2) * 64 + n] + x.w * wsa_t[(k + 3) * 64 + n];
    }
    for (int k = 0; k < 512; k += 4) {
      float4 x = *(const float4*)(x2 + k);
      acc += x.x * wsa_t[(512 + k) * 64 + n] + x.y * wsa_t[(513 + k) * 64 + n] +
             x.z * wsa_t[(514 + k) * 64 + n] + x.w * wsa_t[(515 + k) * 64 + n];
    }
    out[1024 + idx] = acc;
  } else {
    const int bb = blockIdx.x - 256;
    const int b = bb >> 3, kc = bb & 7;
    const int w = t >> 6, lane = t & 63;
    for (int r = w * 16; r < w * 16 + 16; ++r) {
      float v = smat[r * 64 + lane];
      float s = v;
      s += __shfl_xor(s, 1);
      s += __shfl_xor(s, 2);
      s += __shfl_xor(s, 4);
      s += __shfl_xor(s, 8);
      s += __shfl_xor(s, 16);
      s += __shfl_xor(s, 32);
      float d = __shfl(v, r);
      if (lane == 0) av[r] = d / s;
    }
    __syncthreads();
    {
      const int hh = kc * 64 + lane;
      float a = 0.f;
      const float* rp = r_slot + (b * 64 + w * 16) * 512 + hh;
#pragma unroll
      for (int i = 0; i < 16; ++i) a += av[w * 16 + i] * rp[i * 512];
      red[t] = a;
    }
    __syncthreads();
    if (t < 64)
      riv[t] = red[t] + red[t + 64] + red[t + 128] + red[t + 192] +
               c_inte[b * 512 + kc * 64 + t];
    __syncthreads();
    {
      const int n = lane;
      const float* hrow = h + (b * 64 + 63) * 512 + kc * 64;
      float p = 0.f;
#pragma unroll
      for (int k = w * 16; k < w * 16 + 16; ++k) {
        p += riv[k] * wia_t[(kc * 64 + k) * 64 + n];
        p += hrow[k] * wia_t[(512 + kc * 64 + k) * 64 + n];
      }
      red[t] = p;
    }
    __syncthreads();
    if (t < 64)
      atomicAdd(&out[b * 64 + t],
                red[t] + red[t + 64] + red[t + 128] + red[t + 192]);
  }
}

extern "C" void kernel_launch(void* const* d_in, const int* in_sizes, int n_in,
                              void* d_out, int out_size, void* d_ws, size_t ws_size,
                              hipStream_t stream) {
  const float* h      = (const float*)d_in[0];
  const float* c_slot = (const float*)d_in[1];
  const float* c_inte = (const float*)d_in[2];
  const float* W_SF   = (const float*)d_in[3];
  const float* V_SF   = (const float*)d_in[4];
  const float* V1_ID  = (const float*)d_in[5];
  const float* V2_w   = (const float*)d_in[6];
  const float* V2_b   = (const float*)d_in[7];
  const float* W_ID   = (const float*)d_in[8];
  const float* W_ia   = (const float*)d_in[9];
  const float* W_sa   = (const float*)d_in[10];
  float* out = (float*)d_out;

  float* ws     = (float*)d_ws;
  unsigned char* wbp = (unsigned char*)ws;
  float* fpart  = ws + 131072;
  short* v1h    = (short*)(ws + 393216);
  short* sfbuf  = (short*)(ws + 655360);
  float* r_slot = ws + 1179648;
  short* hid    = (short*)(ws + 1703936);
  float* smat   = ws + 2228224;
  float* wia_t  = ws + 2240512;
  float* wsa_t  = ws + 2306048;
  float* wsf_t  = ws + 2371584;
  float* vsf_t  = ws + 2633728;

  k_lin1<<<dim3(64, 17), 256, 0, stream>>>(h, V2_w, V2_b, sfbuf,
                                           W_ID, V1_ID, W_ia, W_sa, W_SF, V_SF,
                                           c_inte, c_slot,
                                           wbp, v1h,
                                           wia_t, wsa_t, wsf_t, vsf_t, fpart);

  for (int it = 0; it < 3; ++it) {
    if (it > 0)
      k_mid<<<256, 512, 0, stream>>>(smat, r_slot, c_inte, c_slot,
                                     wsf_t, vsf_t, fpart);
    k_lin<<<dim3(64, 4), 256, 0, stream>>>(c_slot, fpart, it == 0 ? 8 : 16,
                                           v1h, hid, r_slot, smat);
    k_score<<<dim3(64, 16), 512, 0, stream>>>(hid, sfbuf, wbp, smat,
                                              it == 2 ? out : nullptr);
  }

  k_post<<<384, 256, 0, stream>>>(smat, r_slot, c_inte, h, wia_t, wsa_t, out);
}

// Round 15
// 273.599 us; speedup vs baseline: 1.0225x; 1.0225x over previous
//
#include <hip/hip_runtime.h>
#include <math.h>

// B=16, L=64, H=512, N_LABELS=64, ITERS=3
// Round-28: round-14 base (bf16 hid/sf) with k_score prep remapped to
// 8-elem fragments per thread: fid=t&255 owns a full 16B-contiguous bf16
// octet (one 16B load per operand, one 8B LDS write), plane pair ksb=t>>8.
// Prep: 16 iters x (2x8B ld + 4B ds_write) -> 8 iters x (2x16B ld + 8B
// ds_write): half the load and LDS-write instructions, same VALU.
//
// ws layout (float offsets):
//   wbp 0 [131072] W_ID fp8 (256KB, repacked); fp at 131072 [131072]
//   v1h 393216 [131072] bf16 V1 (hi only)
//   sfbuf 655360 (bf16, 1MB), r_slot 1179648 (f32), hid 1703936 (bf16, 1MB)
//   smat 2228224 [4096]
//   wia_t 2240512, wsa_t 2306048 [65536 each]
//   wsf_t 2371584, vsf_t 2633728 [262144 each]

typedef __attribute__((ext_vector_type(8))) short bf16x8;
typedef __attribute__((ext_vector_type(4))) float f32x4;
typedef long i64fr;
typedef __attribute__((ext_vector_type(2))) long i64x2;

__device__ inline short f2bf(float x) {  // RNE
  unsigned u = __float_as_uint(x);
  unsigned r = (u + 0x7fffu + ((u >> 16) & 1u)) >> 16;
  return (short)r;
}
__device__ inline float bf2f(short s) {
  return __uint_as_float(((unsigned)(unsigned short)s) << 16);
}
__device__ inline unsigned char f2fp8(float x) {  // e4m3 RNE
  unsigned v = __builtin_amdgcn_cvt_pk_fp8_f32(x, x, 0, false);
  return (unsigned char)(v & 0xffu);
}
__device__ inline float ftanh(float x) {
  float t = __expf(2.f * x);
  return 1.f - 2.f * __builtin_amdgcn_rcpf(t + 1.f);
}
__device__ inline bf16x8 pack8hi(float4 a, float4 b) {
  bf16x8 h;
  h[0] = f2bf(a.x); h[1] = f2bf(a.y); h[2] = f2bf(a.z); h[3] = f2bf(a.w);
  h[4] = f2bf(b.x); h[5] = f2bf(b.y); h[6] = f2bf(b.z); h[7] = f2bf(b.w);
  return h;
}

// ---- first linear + all prep + fused first-iteration mid (fp planes) ----
__global__ __launch_bounds__(256) void k_lin1(
    const float* __restrict__ A, const float* __restrict__ rawB,
    const float* __restrict__ bias, short* __restrict__ C,
    const float* __restrict__ W_ID, const float* __restrict__ V1,
    const float* __restrict__ W_ia, const float* __restrict__ W_sa,
    const float* __restrict__ W_SF, const float* __restrict__ V_SF,
    const float* __restrict__ c_inte, const float* __restrict__ c_slot,
    unsigned char* __restrict__ wbp, short* __restrict__ v1h,
    float* __restrict__ wia_t, float* __restrict__ wsa_t,
    float* __restrict__ wsf_t, float* __restrict__ vsf_t,
    float* __restrict__ fp) {
  __shared__ short Ah[2][512];
  __shared__ float tile[64][65];
  __shared__ float riv2[512], red2[256], tm2[64], ts2[64];
  const int nh = blockIdx.y;
  const int t = threadIdx.x;

  if (nh >= 4) {
    const int pid = (nh - 4) * 64 + blockIdx.x;
    if (pid < 256) {  // wbp pack (fp8) layout [ks][w][lane][c][e]
#pragma unroll
      for (int e4 = 0; e4 < 4; ++e4) {
        int idx = pid * 1024 + e4 * 256 + t;
        int e = idx & 7, c = (idx >> 3) & 3;
        int lane = (idx >> 5) & 63, w8 = (idx >> 11) & 7;
        int ks = idx >> 14;
        int g = (w8 * 4 + c) * 16 + (lane & 15);
        int h = ks * 32 + (lane >> 4) * 8 + e;
        wbp[idx] = f2fp8(W_ID[g * 512 + h]);
      }
    } else if (pid < 512) {  // v1 pack (bf16 hi only)
      int p = pid - 256;
#pragma unroll
      for (int e = 0; e < 4; ++e) {
        int idx = p * 1024 + e * 256 + t;
        int j = idx & 7, lane = (idx >> 3) & 63;
        int ntile = (idx >> 9) & 31, kstep = idx >> 14;
        int g = ntile * 16 + (lane & 15);
        int h = kstep * 32 + (lane >> 4) * 8 + j;
        v1h[idx] = f2bf(V1[g * 512 + h]);
      }
    } else if (pid < 672) {  // transposes
      int p = pid - 512;
      const float* tin;
      float* tout;
      int R, C2, c0, r0;
      if (p < 64) {
        tin = W_SF; tout = wsf_t; R = 512; C2 = 512;
        c0 = (p & 7) * 64; r0 = (p >> 3) * 64;
      } else if (p < 128) {
        int q = p - 64;
        tin = V_SF; tout = vsf_t; R = 512; C2 = 512;
        c0 = (q & 7) * 64; r0 = (q >> 3) * 64;
      } else if (p < 144) {
        tin = W_ia; tout = wia_t; R = 64; C2 = 1024;
        c0 = (p - 128) * 64; r0 = 0;
      } else {
        tin = W_sa; tout = wsa_t; R = 64; C2 = 1024;
        c0 = (p - 144) * 64; r0 = 0;
      }
      const int tx = t & 63, ty = t >> 6;
#pragma unroll
      for (int it2 = 0; it2 < 16; ++it2) {
        int rl = ty + it2 * 4;
        tile[rl][tx] = tin[(r0 + rl) * C2 + c0 + tx];
      }
      __syncthreads();
#pragma unroll
      for (int it2 = 0; it2 < 16; ++it2) {
        int cl = ty + it2 * 4;
        tout[(c0 + cl) * R + r0 + tx] = tile[tx][cl];
      }
    } else if (pid < 800) {  // fused first-mid: one (b,hc) chunk each (nch=8)
      const int q = pid - 672;
      const int b = q >> 3, hc = q & 7;
      const int hl = t & 63, kq = t >> 6;  // kq in 0..3
      riv2[t] = c_inte[b * 512 + t];
      riv2[t + 256] = c_inte[b * 512 + 256 + t];
      __syncthreads();
      {  // tm[hl] = sum_k riv[k] * W_SF[hc*64+hl][k]
        const float* wrow = W_SF + (hc * 64 + hl) * 512 + kq * 128;
        float p = 0.f;
#pragma unroll 8
        for (int k = 0; k < 128; k += 4) {
          float4 wv = *(const float4*)(wrow + k);
          p += wv.x * riv2[kq * 128 + k] + wv.y * riv2[kq * 128 + k + 1] +
               wv.z * riv2[kq * 128 + k + 2] + wv.w * riv2[kq * 128 + k + 3];
        }
        red2[t] = p;
      }
      __syncthreads();
      if (t < 64) tm2[t] = red2[t] + red2[t + 64] + red2[t + 128] + red2[t + 192];
      __syncthreads();
      {  // ts[hl] = sum_l tanh(c_slot[b,l,hc*64+hl] + tm[hl])
        float tmph = tm2[hl];
        const float* cp = c_slot + (b * 64 + kq * 16) * 512 + hc * 64 + hl;
        float s = 0.f;
#pragma unroll
        for (int l = 0; l < 16; ++l) s += ftanh(cp[l * 512] + tmph);
        red2[t] = s;
      }
      __syncthreads();
      if (t < 64) ts2[t] = red2[t] + red2[t + 64] + red2[t + 128] + red2[t + 192];
      __syncthreads();
      {  // fp[(b*8+hc)*512 + to] = sum_k ts[k] * V_SF[to][hc*64+k]
#pragma unroll
        for (int half = 0; half < 2; ++half) {
          int to = t + half * 256;
          const float* vrow = V_SF + to * 512 + hc * 64;
          float p = 0.f;
#pragma unroll 8
          for (int k = 0; k < 64; k += 4) {
            float4 vv = *(const float4*)(vrow + k);
            p += vv.x * ts2[k] + vv.y * ts2[k + 1] + vv.z * ts2[k + 2] +
                 vv.w * ts2[k + 3];
          }
          fp[(b * 8 + hc) * 512 + to] = p;
        }
      }
    }
    return;
  }

  // ---- gemm planes (nh<4): raw f32 B, bf16-hi only; bf16 C out ----
  const int m0 = blockIdx.x * 16;
  const int w = t >> 6, lane = t & 63;
  const int lq = lane >> 4, lm = lane & 15;
  f32x4 acc[2];
#pragma unroll
  for (int c = 0; c < 2; ++c) acc[c] = (f32x4){0.f, 0.f, 0.f, 0.f};

  const int nt0 = nh * 8 + w * 2;
  const float* vb0 = rawB + (nt0 * 16 + lm) * 512 + lq * 8;
  const float* vb1 = vb0 + 16 * 512;

  const int la = t >> 2, j0 = (t & 3) * 2;
  const int m = la & 15, kk = (la >> 4) * 8 + j0;
  const float* abase = A + (m0 + m) * 512 + kk;
  float2 x = *(const float2*)abase;

  for (int ks = 0; ks < 16; ++ks) {
    const int buf = ks & 1;
    float4 q0 = *(const float4*)(vb0 + ks * 32);
    float4 q1 = *(const float4*)(vb0 + ks * 32 + 4);
    float4 p0 = *(const float4*)(vb1 + ks * 32);
    float4 p1 = *(const float4*)(vb1 + ks * 32 + 4);
    float2 xn = x;
    if (ks < 15) xn = *(const float2*)(abase + (ks + 1) * 32);
    *(short2*)&Ah[buf][t * 2] = make_short2(f2bf(x.x), f2bf(x.y));
    bf16x8 b0h = pack8hi(q0, q1);
    bf16x8 b1h = pack8hi(p0, p1);
    __syncthreads();
    bf16x8 ah = *(const bf16x8*)&Ah[buf][lane * 8];
    acc[0] = __builtin_amdgcn_mfma_f32_16x16x32_bf16(ah, b0h, acc[0], 0, 0, 0);
    acc[1] = __builtin_amdgcn_mfma_f32_16x16x32_bf16(ah, b1h, acc[1], 0, 0, 0);
    x = xn;
  }
#pragma unroll
  for (int c = 0; c < 2; ++c)
#pragma unroll
    for (int reg = 0; reg < 4; ++reg) {
      int mm = m0 + lq * 4 + reg;
      int n = (nt0 + c) * 16 + lm;
      C[mm * 512 + n] = f2bf(acc[c][reg] + bias[n]);
    }
}

// ---- bf16 MFMA linear; fl = sum of nch fp partials; bf16 C out ----
// grid (64, 4); A = f[b,:] (x) c_slot, nh==0 writes r_slot (f32), zeroes smat.
__global__ __launch_bounds__(256) void k_lin(const float* __restrict__ c_slot,
                                             const float* __restrict__ fp,
                                             int nch,
                                             const short* __restrict__ bh,
                                             short* __restrict__ C,
                                             float* __restrict__ rs_out,
                                             float* __restrict__ smat0) {
  __shared__ short Ah[2][512];
  __shared__ float fl[512];
  const int m0 = blockIdx.x * 16;
  const int nh = blockIdx.y;
  const int t = threadIdx.x;
  if (nh == 0 && blockIdx.x < 8) {
    smat0[blockIdx.x * 512 + t] = 0.f;
    smat0[blockIdx.x * 512 + 256 + t] = 0.f;
  }
  {
    const float* fb = fp + (blockIdx.x >> 2) * nch * 512;
    float s0 = 0.f, s1 = 0.f;
    for (int hc = 0; hc < nch; ++hc) {
      s0 += fb[hc * 512 + t];
      s1 += fb[hc * 512 + 256 + t];
    }
    fl[t] = s0;
    fl[t + 256] = s1;
  }
  const int w = t >> 6, lane = t & 63;
  const int lq = lane >> 4, lm = lane & 15;
  f32x4 acc[2];
#pragma unroll
  for (int c = 0; c < 2; ++c) acc[c] = (f32x4){0.f, 0.f, 0.f, 0.f};

  const bf16x8* gbh = (const bf16x8*)bh + (nh * 8 + w * 2) * 64 + lane;

  const int la = t >> 2, j0 = (t & 3) * 2;
  const int m = la & 15, kk = (la >> 4) * 8 + j0;
  const float* abase = c_slot + (m0 + m) * 512 + kk;
  float* rbase = rs_out + (m0 + m) * 512 + kk;
  __syncthreads();  // fl ready
  float2 x = *(const float2*)abase;

  for (int ks = 0; ks < 16; ++ks) {
    const int buf = ks & 1;
    bf16x8 b0h = gbh[ks * 2048];
    bf16x8 b1h = gbh[ks * 2048 + 64];
    float2 xn = x;
    if (ks < 15) xn = *(const float2*)(abase + (ks + 1) * 32);
    float a0 = x.x * fl[ks * 32 + kk];
    float a1 = x.y * fl[ks * 32 + kk + 1];
    if (nh == 0) *(float2*)(rbase + ks * 32) = make_float2(a0, a1);
    *(short2*)&Ah[buf][t * 2] = make_short2(f2bf(a0), f2bf(a1));
    __syncthreads();
    bf16x8 ah = *(const bf16x8*)&Ah[buf][lane * 8];
    acc[0] = __builtin_amdgcn_mfma_f32_16x16x32_bf16(ah, b0h, acc[0], 0, 0, 0);
    acc[1] = __builtin_amdgcn_mfma_f32_16x16x32_bf16(ah, b1h, acc[1], 0, 0, 0);
    x = xn;
  }
#pragma unroll
  for (int c = 0; c < 2; ++c)
#pragma unroll
    for (int reg = 0; reg < 4; ++reg) {
      int mm = m0 + lq * 4 + reg;
      int n = nh * 128 + (w * 2 + c) * 16 + lm;
      C[mm * 512 + n] = f2bf(acc[c][reg]);
    }
}

// ---- per-iteration mid chain (it=1,2): 256 blocks = (b:16) x (hcc:16) ----
// Writes partials fp[(b*16+hcc)*512 + :] (no atomics, no pre-zeroing).
__global__ __launch_bounds__(512) void k_mid(const float* __restrict__ smat,
                                             const float* __restrict__ r_slot,
                                             const float* __restrict__ c_inte,
                                             const float* __restrict__ c_slot,
                                             const float* __restrict__ wsf_t,
                                             const float* __restrict__ vsf_t,
                                             float* __restrict__ fp) {
  __shared__ float av[64];
  __shared__ float riv[512];
  __shared__ float red[512];
  __shared__ float tm[32], ts[32];
  const int b = blockIdx.x >> 4, hcc = blockIdx.x & 15;
  const int t = threadIdx.x;

  if (t < 256) {
    int w = t >> 6, lane = t & 63;
    for (int r = w * 16; r < w * 16 + 16; ++r) {
      float v = smat[r * 64 + lane];
      float s = v;
      s += __shfl_xor(s, 1);
      s += __shfl_xor(s, 2);
      s += __shfl_xor(s, 4);
      s += __shfl_xor(s, 8);
      s += __shfl_xor(s, 16);
      s += __shfl_xor(s, 32);
      float d = __shfl(v, r);
      if (lane == 0) av[r] = d / s;
    }
  }
  __syncthreads();
  {
    float a = 0.f;
    const float* rp = r_slot + b * 64 * 512 + t;
#pragma unroll 8
    for (int i = 0; i < 64; ++i) a += av[i] * rp[i * 512];
    riv[t] = a + c_inte[b * 512 + t];
  }
  __syncthreads();
  const int hl2 = t & 31, kq2 = t >> 5;  // 16 k-groups of 32
  {
    const float* wp = wsf_t + hcc * 32 + hl2;
    float p = 0.f;
#pragma unroll 8
    for (int k = kq2 * 32; k < kq2 * 32 + 32; ++k) p += riv[k] * wp[k * 512];
    red[t] = p;
  }
  __syncthreads();
  if (t < 32) {
    float s = 0.f;
#pragma unroll
    for (int q = 0; q < 16; ++q) s += red[q * 32 + t];
    tm[t] = s;
  }
  __syncthreads();
  {
    float tmph = tm[hl2];
    const float* cp = c_slot + (b * 64 + kq2 * 4) * 512 + hcc * 32 + hl2;
    float s = 0.f;
#pragma unroll
    for (int l = 0; l < 4; ++l) s += ftanh(cp[l * 512] + tmph);
    red[t] = s;
  }
  __syncthreads();
  if (t < 32) {
    float s = 0.f;
#pragma unroll
    for (int q = 0; q < 16; ++q) s += red[q * 32 + t];
    ts[t] = s;
  }
  __syncthreads();
  {
    const float* vp = vsf_t + (hcc * 32) * 512 + t;
    float p = 0.f;
#pragma unroll 8
    for (int k = 0; k < 32; ++k) p += ts[k] * vp[k * 512];
    fp[blockIdx.x * 512 + t] = p;
  }
}

// ---- dominant kernel v8-fp8: bf16 inputs, 8-elem-per-thread prep ----
__global__ __launch_bounds__(512, 4) void k_score(
    const short* __restrict__ hid, const short* __restrict__ sf,
    const unsigned char* __restrict__ wbp, float* __restrict__ smat,
    float* __restrict__ oz) {
  __shared__ unsigned char As[16][2048];  // 32 KB
  __shared__ float red[8][64];
  const int i = blockIdx.x, b = blockIdx.y;
  const int t = threadIdx.x;
  if (oz && i == 1 && b < 2) oz[b * 512 + t] = 0.f;
  const int w = t >> 6, lane = t & 63;
  const int lq = lane >> 4, lm = lane & 15;

  f32x4 acc[4][4];
#pragma unroll
  for (int r = 0; r < 4; ++r)
#pragma unroll
    for (int c = 0; c < 4; ++c) acc[r][c] = (f32x4){0.f, 0.f, 0.f, 0.f};

  const short* hrow = hid + (b * 64 + i) * 512;
  const short* sfb = sf + b * 64 * 512;

  // prep: thread owns full 8-elem fragment fid = t&255, plane pair ksb = t>>8
  const int fid = t & 255, ksb = t >> 8;
  const int am = (fid >> 6) * 16 + (fid & 15);
  const int aq = (fid >> 4) & 3;
  const int aoff = fid * 8;  // byte offset of 8B dest in plane

  const short* hp0 = hrow + aq * 8;
  const short* sp0 = sfb + am * 512 + aq * 8;

  // wbp layout: [ks][w:8][lane:64][c:4][8B]; per lane 32B contiguous.
  const i64x2* gb = (const i64x2*)wbp + (w * 64 + lane) * 2;
  i64x2 nba = gb[0];      // c0,c1
  i64x2 nbb = gb[1];      // c2,c3

#pragma unroll 4
  for (int it2 = 0; it2 < 8; ++it2) {
    const int ks = it2 * 2 + ksb;
    bf16x8 hv = *(const bf16x8*)(hp0 + ks * 32);
    bf16x8 sv = *(const bf16x8*)(sp0 + ks * 32);
    unsigned pk0 = __builtin_amdgcn_cvt_pk_fp8_f32(
        ftanh(bf2f(hv[0]) + bf2f(sv[0])), ftanh(bf2f(hv[1]) + bf2f(sv[1])),
        0, false);
    pk0 = __builtin_amdgcn_cvt_pk_fp8_f32(
        ftanh(bf2f(hv[2]) + bf2f(sv[2])), ftanh(bf2f(hv[3]) + bf2f(sv[3])),
        pk0, true);
    unsigned pk1 = __builtin_amdgcn_cvt_pk_fp8_f32(
        ftanh(bf2f(hv[4]) + bf2f(sv[4])), ftanh(bf2f(hv[5]) + bf2f(sv[5])),
        0, false);
    pk1 = __builtin_amdgcn_cvt_pk_fp8_f32(
        ftanh(bf2f(hv[6]) + bf2f(sv[6])), ftanh(bf2f(hv[7]) + bf2f(sv[7])),
        pk1, true);
    uint2 pk;
    pk.x = pk0;
    pk.y = pk1;
    *(uint2*)&As[ks][aoff] = pk;
  }
  __syncthreads();

  for (int ks = 0; ks < 16; ++ks) {
    i64fr b0 = nba.x, b1 = nba.y, b2 = nbb.x, b3 = nbb.y;
    if (ks < 15) {
      nba = gb[(ks + 1) * 1024];
      nbb = gb[(ks + 1) * 1024 + 1];
    }
    i64fr af0 = *(const i64fr*)&As[ks][(0 * 64 + lane) * 8];
    i64fr af1 = *(const i64fr*)&As[ks][(1 * 64 + lane) * 8];
    i64fr af2 = *(const i64fr*)&As[ks][(2 * 64 + lane) * 8];
    i64fr af3 = *(const i64fr*)&As[ks][(3 * 64 + lane) * 8];
    acc[0][0] = __builtin_amdgcn_mfma_f32_16x16x32_fp8_fp8(af0, b0, acc[0][0], 0, 0, 0);
    acc[1][0] = __builtin_amdgcn_mfma_f32_16x16x32_fp8_fp8(af1, b0, acc[1][0], 0, 0, 0);
    acc[2][0] = __builtin_amdgcn_mfma_f32_16x16x32_fp8_fp8(af2, b0, acc[2][0], 0, 0, 0);
    acc[3][0] = __builtin_amdgcn_mfma_f32_16x16x32_fp8_fp8(af3, b0, acc[3][0], 0, 0, 0);
    acc[0][1] = __builtin_amdgcn_mfma_f32_16x16x32_fp8_fp8(af0, b1, acc[0][1], 0, 0, 0);
    acc[1][1] = __builtin_amdgcn_mfma_f32_16x16x32_fp8_fp8(af1, b1, acc[1][1], 0, 0, 0);
    acc[2][1] = __builtin_amdgcn_mfma_f32_16x16x32_fp8_fp8(af2, b1, acc[2][1], 0, 0, 0);
    acc[3][1] = __builtin_amdgcn_mfma_f32_16x16x32_fp8_fp8(af3, b1, acc[3][1], 0, 0, 0);
    acc[0][2] = __builtin_amdgcn_mfma_f32_16x16x32_fp8_fp8(af0, b2, acc[0][2], 0, 0, 0);
    acc[1][2] = __builtin_amdgcn_mfma_f32_16x16x32_fp8_fp8(af1, b2, acc[1][2], 0, 0, 0);
    acc[2][2] = __builtin_amdgcn_mfma_f32_16x16x32_fp8_fp8(af2, b2, acc[2][2], 0, 0, 0);
    acc[3][2] = __builtin_amdgcn_mfma_f32_16x16x32_fp8_fp8(af3, b2, acc[3][2], 0, 0, 0);
    acc[0][3] = __builtin_amdgcn_mfma_f32_16x16x32_fp8_fp8(af0, b3, acc[0][3], 0, 0, 0);
    acc[1][3] = __builtin_amdgcn_mfma_f32_16x16x32_fp8_fp8(af1, b3, acc[1][3], 0, 0, 0);
    acc[2][3] = __builtin_amdgcn_mfma_f32_16x16x32_fp8_fp8(af2, b3, acc[2][3], 0, 0, 0);
    acc[3][3] = __builtin_amdgcn_mfma_f32_16x16x32_fp8_fp8(af3, b3, acc[3][3], 0, 0, 0);
  }

#pragma unroll
  for (int r = 0; r < 4; ++r) {
#pragma unroll
    for (int reg = 0; reg < 4; ++reg) {
      float v = __expf(acc[r][0][reg]) + __expf(acc[r][1][reg]) +
                __expf(acc[r][2][reg]) + __expf(acc[r][3][reg]);
      v += __shfl_down(v, 8, 16);
      v += __shfl_down(v, 4, 16);
      v += __shfl_down(v, 2, 16);
      v += __shfl_down(v, 1, 16);
      if (lm == 0) red[w][r * 16 + lq * 4 + reg] = v;
    }
  }
  __syncthreads();
  if (t < 64) {
    float s = 0.f;
#pragma unroll
    for (int ww = 0; ww < 8; ++ww) s += red[ww][t];
    atomicAdd(&smat[i * 64 + t], s);
  }
}

// ---- post: k_slot (bx<256) + k_fin (bx>=256) merged (round-0 form) ----
__global__ __launch_bounds__(256) void k_post(const float* __restrict__ smat,
                                              const float* __restrict__ r_slot,
                                              const float* __restrict__ c_inte,
                                              const float* __restrict__ h,
                                              const float* __restrict__ wia_t,
                                              const float* __restrict__ wsa_t,
                                              float* __restrict__ out) {
  __shared__ float av[64], riv[64], red[256];
  const int t = threadIdx.x;
  if (blockIdx.x < 256) {
    int idx = blockIdx.x * 256 + t;  // 65536
    int ml = idx >> 6, n = idx & 63;
    const float* x1 = h + ml * 512;
    const float* x2 = r_slot + ml * 512;
    float acc = 0.f;
    for (int k = 0; k < 512; k += 4) {
      float4 x = *(const float4*)(x1 + k);
      acc += x.x * wsa_t[k * 64 + n] + x.y * wsa_t[(k + 1) * 64 + n] +
             x.z * wsa_t[(k + 2) * 64 + n] + x.w * wsa_t[(k + 3) * 64 + n];
    }
    for (int k = 0; k < 512; k += 4) {
      float4 x = *(const float4*)(x2 + k);
      acc += x.x * wsa_t[(512 + k) * 64 + n] + x.y * wsa_t[(513 + k) * 64 + n] +
             x.z * wsa_t[(514 + k) * 64 + n] + x.w * wsa_t[(515 + k) * 64 + n];
    }
    out[1024 + idx] = acc;
  } else {
    const int bb = blockIdx.x - 256;
    const int b = bb >> 3, kc = bb & 7;
    const int w = t >> 6, lane = t & 63;
    for (int r = w * 16; r < w * 16 + 16; ++r) {
      float v = smat[r * 64 + lane];
      float s = v;
      s += __shfl_xor(s, 1);
      s += __shfl_xor(s, 2);
      s += __shfl_xor(s, 4);
      s += __shfl_xor(s, 8);
      s += __shfl_xor(s, 16);
      s += __shfl_xor(s, 32);
      float d = __shfl(v, r);
      if (lane == 0) av[r] = d / s;
    }
    __syncthreads();
    {
      const int hh = kc * 64 + lane;
      float a = 0.f;
      const float* rp = r_slot + (b * 64 + w * 16) * 512 + hh;
#pragma unroll
      for (int i = 0; i < 16; ++i) a += av[w * 16 + i] * rp[i * 512];
      red[t] = a;
    }
    __syncthreads();
    if (t < 64)
      riv[t] = red[t] + red[t + 64] + red[t + 128] + red[t + 192] +
               c_inte[b * 512 + kc * 64 + t];
    __syncthreads();
    {
      const int n = lane;
      const float* hrow = h + (b * 64 + 63) * 512 + kc * 64;
      float p = 0.f;
#pragma unroll
      for (int k = w * 16; k < w * 16 + 16; ++k) {
        p += riv[k] * wia_t[(kc * 64 + k) * 64 + n];
        p += hrow[k] * wia_t[(512 + kc * 64 + k) * 64 + n];
      }
      red[t] = p;
    }
    __syncthreads();
    if (t < 64)
      atomicAdd(&out[b * 64 + t],
                red[t] + red[t + 64] + red[t + 128] + red[t + 192]);
  }
}

extern "C" void kernel_launch(void* const* d_in, const int* in_sizes, int n_in,
                              void* d_out, int out_size, void* d_ws, size_t ws_size,
                              hipStream_t stream) {
  const float* h      = (const float*)d_in[0];
  const float* c_slot = (const float*)d_in[1];
  const float* c_inte = (const float*)d_in[2];
  const float* W_SF   = (const float*)d_in[3];
  const float* V_SF   = (const float*)d_in[4];
  const float* V1_ID  = (const float*)d_in[5];
  const float* V2_w   = (const float*)d_in[6];
  const float* V2_b   = (const float*)d_in[7];
  const float* W_ID   = (const float*)d_in[8];
  const float* W_ia   = (const float*)d_in[9];
  const float* W_sa   = (const float*)d_in[10];
  float* out = (float*)d_out;

  float* ws     = (float*)d_ws;
  unsigned char* wbp = (unsigned char*)ws;
  float* fpart  = ws + 131072;
  short* v1h    = (short*)(ws + 393216);
  short* sfbuf  = (short*)(ws + 655360);
  float* r_slot = ws + 1179648;
  short* hid    = (short*)(ws + 1703936);
  float* smat   = ws + 2228224;
  float* wia_t  = ws + 2240512;
  float* wsa_t  = ws + 2306048;
  float* wsf_t  = ws + 2371584;
  float* vsf_t  = ws + 2633728;

  k_lin1<<<dim3(64, 17), 256, 0, stream>>>(h, V2_w, V2_b, sfbuf,
                                           W_ID, V1_ID, W_ia, W_sa, W_SF, V_SF,
                                           c_inte, c_slot,
                                           wbp, v1h,
                                           wia_t, wsa_t, wsf_t, vsf_t, fpart);

  for (int it = 0; it < 3; ++it) {
    if (it > 0)
      k_mid<<<256, 512, 0, stream>>>(smat, r_slot, c_inte, c_slot,
                                     wsf_t, vsf_t, fpart);
    k_lin<<<dim3(64, 4), 256, 0, stream>>>(c_slot, fpart, it == 0 ? 8 : 16,
                                           v1h, hid, r_slot, smat);
    k_score<<<dim3(64, 16), 512, 0, stream>>>(hid, sfbuf, wbp, smat,
                                              it == 2 ? out : nullptr);
  }

  k_post<<<384, 256, 0, stream>>>(smat, r_slot, c_inte, h, wia_t, wsa_t, out);
}

// Round 16
// 272.279 us; speedup vs baseline: 1.0274x; 1.0048x over previous
//
#include <hip/hip_runtime.h>
#include <math.h>

// B=16, L=64, H=512, N_LABELS=64, ITERS=3
// Round-29: round-15 base (273.6us). k_lin occupancy doubled: grid (64,4)
// -> (64,8), 1 n-tile per wave (acc f32x4, 1 B-load + 1 MFMA per ks).
// 512 blocks = 2 blocks/CU = 2 waves/SIMD so barrier drains overlap across
// blocks. A-staging duplicated (cheap); everything else untouched.
//
// ws layout (float offsets):
//   wbp 0 [131072] W_ID fp8 (256KB, repacked); fp at 131072 [131072]
//   v1h 393216 [131072] bf16 V1 (hi only)
//   sfbuf 655360 (bf16, 1MB), r_slot 1179648 (f32), hid 1703936 (bf16, 1MB)
//   smat 2228224 [4096]
//   wia_t 2240512, wsa_t 2306048 [65536 each]
//   wsf_t 2371584, vsf_t 2633728 [262144 each]

typedef __attribute__((ext_vector_type(8))) short bf16x8;
typedef __attribute__((ext_vector_type(4))) float f32x4;
typedef long i64fr;
typedef __attribute__((ext_vector_type(2))) long i64x2;

__device__ inline short f2bf(float x) {  // RNE
  unsigned u = __float_as_uint(x);
  unsigned r = (u + 0x7fffu + ((u >> 16) & 1u)) >> 16;
  return (short)r;
}
__device__ inline float bf2f(short s) {
  return __uint_as_float(((unsigned)(unsigned short)s) << 16);
}
__device__ inline unsigned char f2fp8(float x) {  // e4m3 RNE
  unsigned v = __builtin_amdgcn_cvt_pk_fp8_f32(x, x, 0, false);
  return (unsigned char)(v & 0xffu);
}
__device__ inline float ftanh(float x) {
  float t = __expf(2.f * x);
  return 1.f - 2.f * __builtin_amdgcn_rcpf(t + 1.f);
}
__device__ inline bf16x8 pack8hi(float4 a, float4 b) {
  bf16x8 h;
  h[0] = f2bf(a.x); h[1] = f2bf(a.y); h[2] = f2bf(a.z); h[3] = f2bf(a.w);
  h[4] = f2bf(b.x); h[5] = f2bf(b.y); h[6] = f2bf(b.z); h[7] = f2bf(b.w);
  return h;
}

// ---- first linear + all prep + fused first-iteration mid (fp planes) ----
__global__ __launch_bounds__(256) void k_lin1(
    const float* __restrict__ A, const float* __restrict__ rawB,
    const float* __restrict__ bias, short* __restrict__ C,
    const float* __restrict__ W_ID, const float* __restrict__ V1,
    const float* __restrict__ W_ia, const float* __restrict__ W_sa,
    const float* __restrict__ W_SF, const float* __restrict__ V_SF,
    const float* __restrict__ c_inte, const float* __restrict__ c_slot,
    unsigned char* __restrict__ wbp, short* __restrict__ v1h,
    float* __restrict__ wia_t, float* __restrict__ wsa_t,
    float* __restrict__ wsf_t, float* __restrict__ vsf_t,
    float* __restrict__ fp) {
  __shared__ short Ah[2][512];
  __shared__ float tile[64][65];
  __shared__ float riv2[512], red2[256], tm2[64], ts2[64];
  const int nh = blockIdx.y;
  const int t = threadIdx.x;

  if (nh >= 4) {
    const int pid = (nh - 4) * 64 + blockIdx.x;
    if (pid < 256) {  // wbp pack (fp8) layout [ks][w][lane][c][e]
#pragma unroll
      for (int e4 = 0; e4 < 4; ++e4) {
        int idx = pid * 1024 + e4 * 256 + t;
        int e = idx & 7, c = (idx >> 3) & 3;
        int lane = (idx >> 5) & 63, w8 = (idx >> 11) & 7;
        int ks = idx >> 14;
        int g = (w8 * 4 + c) * 16 + (lane & 15);
        int h = ks * 32 + (lane >> 4) * 8 + e;
        wbp[idx] = f2fp8(W_ID[g * 512 + h]);
      }
    } else if (pid < 512) {  // v1 pack (bf16 hi only)
      int p = pid - 256;
#pragma unroll
      for (int e = 0; e < 4; ++e) {
        int idx = p * 1024 + e * 256 + t;
        int j = idx & 7, lane = (idx >> 3) & 63;
        int ntile = (idx >> 9) & 31, kstep = idx >> 14;
        int g = ntile * 16 + (lane & 15);
        int h = kstep * 32 + (lane >> 4) * 8 + j;
        v1h[idx] = f2bf(V1[g * 512 + h]);
      }
    } else if (pid < 672) {  // transposes
      int p = pid - 512;
      const float* tin;
      float* tout;
      int R, C2, c0, r0;
      if (p < 64) {
        tin = W_SF; tout = wsf_t; R = 512; C2 = 512;
        c0 = (p & 7) * 64; r0 = (p >> 3) * 64;
      } else if (p < 128) {
        int q = p - 64;
        tin = V_SF; tout = vsf_t; R = 512; C2 = 512;
        c0 = (q & 7) * 64; r0 = (q >> 3) * 64;
      } else if (p < 144) {
        tin = W_ia; tout = wia_t; R = 64; C2 = 1024;
        c0 = (p - 128) * 64; r0 = 0;
      } else {
        tin = W_sa; tout = wsa_t; R = 64; C2 = 1024;
        c0 = (p - 144) * 64; r0 = 0;
      }
      const int tx = t & 63, ty = t >> 6;
#pragma unroll
      for (int it2 = 0; it2 < 16; ++it2) {
        int rl = ty + it2 * 4;
        tile[rl][tx] = tin[(r0 + rl) * C2 + c0 + tx];
      }
      __syncthreads();
#pragma unroll
      for (int it2 = 0; it2 < 16; ++it2) {
        int cl = ty + it2 * 4;
        tout[(c0 + cl) * R + r0 + tx] = tile[tx][cl];
      }
    } else if (pid < 800) {  // fused first-mid: one (b,hc) chunk each (nch=8)
      const int q = pid - 672;
      const int b = q >> 3, hc = q & 7;
      const int hl = t & 63, kq = t >> 6;  // kq in 0..3
      riv2[t] = c_inte[b * 512 + t];
      riv2[t + 256] = c_inte[b * 512 + 256 + t];
      __syncthreads();
      {  // tm[hl] = sum_k riv[k] * W_SF[hc*64+hl][k]
        const float* wrow = W_SF + (hc * 64 + hl) * 512 + kq * 128;
        float p = 0.f;
#pragma unroll 8
        for (int k = 0; k < 128; k += 4) {
          float4 wv = *(const float4*)(wrow + k);
          p += wv.x * riv2[kq * 128 + k] + wv.y * riv2[kq * 128 + k + 1] +
               wv.z * riv2[kq * 128 + k + 2] + wv.w * riv2[kq * 128 + k + 3];
        }
        red2[t] = p;
      }
      __syncthreads();
      if (t < 64) tm2[t] = red2[t] + red2[t + 64] + red2[t + 128] + red2[t + 192];
      __syncthreads();
      {  // ts[hl] = sum_l tanh(c_slot[b,l,hc*64+hl] + tm[hl])
        float tmph = tm2[hl];
        const float* cp = c_slot + (b * 64 + kq * 16) * 512 + hc * 64 + hl;
        float s = 0.f;
#pragma unroll
        for (int l = 0; l < 16; ++l) s += ftanh(cp[l * 512] + tmph);
        red2[t] = s;
      }
      __syncthreads();
      if (t < 64) ts2[t] = red2[t] + red2[t + 64] + red2[t + 128] + red2[t + 192];
      __syncthreads();
      {  // fp[(b*8+hc)*512 + to] = sum_k ts[k] * V_SF[to][hc*64+k]
#pragma unroll
        for (int half = 0; half < 2; ++half) {
          int to = t + half * 256;
          const float* vrow = V_SF + to * 512 + hc * 64;
          float p = 0.f;
#pragma unroll 8
          for (int k = 0; k < 64; k += 4) {
            float4 vv = *(const float4*)(vrow + k);
            p += vv.x * ts2[k] + vv.y * ts2[k + 1] + vv.z * ts2[k + 2] +
                 vv.w * ts2[k + 3];
          }
          fp[(b * 8 + hc) * 512 + to] = p;
        }
      }
    }
    return;
  }

  // ---- gemm planes (nh<4): raw f32 B, bf16-hi only; bf16 C out ----
  const int m0 = blockIdx.x * 16;
  const int w = t >> 6, lane = t & 63;
  const int lq = lane >> 4, lm = lane & 15;
  f32x4 acc[2];
#pragma unroll
  for (int c = 0; c < 2; ++c) acc[c] = (f32x4){0.f, 0.f, 0.f, 0.f};

  const int nt0 = nh * 8 + w * 2;
  const float* vb0 = rawB + (nt0 * 16 + lm) * 512 + lq * 8;
  const float* vb1 = vb0 + 16 * 512;

  const int la = t >> 2, j0 = (t & 3) * 2;
  const int m = la & 15, kk = (la >> 4) * 8 + j0;
  const float* abase = A + (m0 + m) * 512 + kk;
  float2 x = *(const float2*)abase;

  for (int ks = 0; ks < 16; ++ks) {
    const int buf = ks & 1;
    float4 q0 = *(const float4*)(vb0 + ks * 32);
    float4 q1 = *(const float4*)(vb0 + ks * 32 + 4);
    float4 p0 = *(const float4*)(vb1 + ks * 32);
    float4 p1 = *(const float4*)(vb1 + ks * 32 + 4);
    float2 xn = x;
    if (ks < 15) xn = *(const float2*)(abase + (ks + 1) * 32);
    *(short2*)&Ah[buf][t * 2] = make_short2(f2bf(x.x), f2bf(x.y));
    bf16x8 b0h = pack8hi(q0, q1);
    bf16x8 b1h = pack8hi(p0, p1);
    __syncthreads();
    bf16x8 ah = *(const bf16x8*)&Ah[buf][lane * 8];
    acc[0] = __builtin_amdgcn_mfma_f32_16x16x32_bf16(ah, b0h, acc[0], 0, 0, 0);
    acc[1] = __builtin_amdgcn_mfma_f32_16x16x32_bf16(ah, b1h, acc[1], 0, 0, 0);
    x = xn;
  }
#pragma unroll
  for (int c = 0; c < 2; ++c)
#pragma unroll
    for (int reg = 0; reg < 4; ++reg) {
      int mm = m0 + lq * 4 + reg;
      int n = (nt0 + c) * 16 + lm;
      C[mm * 512 + n] = f2bf(acc[c][reg] + bias[n]);
    }
}

// ---- bf16 MFMA linear; grid (64,8), 1 n-tile per wave, 2 blocks/CU ----
// A = f[b,:] (x) c_slot; nh==0 writes r_slot (f32), zeroes smat.
__global__ __launch_bounds__(256) void k_lin(const float* __restrict__ c_slot,
                                             const float* __restrict__ fp,
                                             int nch,
                                             const short* __restrict__ bh,
                                             short* __restrict__ C,
                                             float* __restrict__ rs_out,
                                             float* __restrict__ smat0) {
  __shared__ short Ah[2][512];
  __shared__ float fl[512];
  const int m0 = blockIdx.x * 16;
  const int nh = blockIdx.y;
  const int t = threadIdx.x;
  if (nh == 0 && blockIdx.x < 8) {
    smat0[blockIdx.x * 512 + t] = 0.f;
    smat0[blockIdx.x * 512 + 256 + t] = 0.f;
  }
  {
    const float* fb = fp + (blockIdx.x >> 2) * nch * 512;
    float s0 = 0.f, s1 = 0.f;
    for (int hc = 0; hc < nch; ++hc) {
      s0 += fb[hc * 512 + t];
      s1 += fb[hc * 512 + 256 + t];
    }
    fl[t] = s0;
    fl[t + 256] = s1;
  }
  const int w = t >> 6, lane = t & 63;
  const int lq = lane >> 4, lm = lane & 15;
  f32x4 acc = (f32x4){0.f, 0.f, 0.f, 0.f};

  const int nt = nh * 4 + w;  // one n-tile per wave
  const bf16x8* gbh = (const bf16x8*)bh + nt * 64 + lane;

  const int la = t >> 2, j0 = (t & 3) * 2;
  const int m = la & 15, kk = (la >> 4) * 8 + j0;
  const float* abase = c_slot + (m0 + m) * 512 + kk;
  float* rbase = rs_out + (m0 + m) * 512 + kk;
  __syncthreads();  // fl ready
  float2 x = *(const float2*)abase;

  for (int ks = 0; ks < 16; ++ks) {
    const int buf = ks & 1;
    bf16x8 b0h = gbh[ks * 2048];
    float2 xn = x;
    if (ks < 15) xn = *(const float2*)(abase + (ks + 1) * 32);
    float a0 = x.x * fl[ks * 32 + kk];
    float a1 = x.y * fl[ks * 32 + kk + 1];
    if (nh == 0) *(float2*)(rbase + ks * 32) = make_float2(a0, a1);
    *(short2*)&Ah[buf][t * 2] = make_short2(f2bf(a0), f2bf(a1));
    __syncthreads();
    bf16x8 ah = *(const bf16x8*)&Ah[buf][lane * 8];
    acc = __builtin_amdgcn_mfma_f32_16x16x32_bf16(ah, b0h, acc, 0, 0, 0);
    x = xn;
  }
#pragma unroll
  for (int reg = 0; reg < 4; ++reg) {
    int mm = m0 + lq * 4 + reg;
    int n = nt * 16 + lm;
    C[mm * 512 + n] = f2bf(acc[reg]);
  }
}

// ---- per-iteration mid chain (it=1,2): 256 blocks = (b:16) x (hcc:16) ----
// Writes partials fp[(b*16+hcc)*512 + :] (no atomics, no pre-zeroing).
__global__ __launch_bounds__(512) void k_mid(const float* __restrict__ smat,
                                             const float* __restrict__ r_slot,
                                             const float* __restrict__ c_inte,
                                             const float* __restrict__ c_slot,
                                             const float* __restrict__ wsf_t,
                                             const float* __restrict__ vsf_t,
                                             float* __restrict__ fp) {
  __shared__ float av[64];
  __shared__ float riv[512];
  __shared__ float red[512];
  __shared__ float tm[32], ts[32];
  const int b = blockIdx.x >> 4, hcc = blockIdx.x & 15;
  const int t = threadIdx.x;

  if (t < 256) {
    int w = t >> 6, lane = t & 63;
    for (int r = w * 16; r < w * 16 + 16; ++r) {
      float v = smat[r * 64 + lane];
      float s = v;
      s += __shfl_xor(s, 1);
      s += __shfl_xor(s, 2);
      s += __shfl_xor(s, 4);
      s += __shfl_xor(s, 8);
      s += __shfl_xor(s, 16);
      s += __shfl_xor(s, 32);
      float d = __shfl(v, r);
      if (lane == 0) av[r] = d / s;
    }
  }
  __syncthreads();
  {
    float a = 0.f;
    const float* rp = r_slot + b * 64 * 512 + t;
#pragma unroll 8
    for (int i = 0; i < 64; ++i) a += av[i] * rp[i * 512];
    riv[t] = a + c_inte[b * 512 + t];
  }
  __syncthreads();
  const int hl2 = t & 31, kq2 = t >> 5;  // 16 k-groups of 32
  {
    const float* wp = wsf_t + hcc * 32 + hl2;
    float p = 0.f;
#pragma unroll 8
    for (int k = kq2 * 32; k < kq2 * 32 + 32; ++k) p += riv[k] * wp[k * 512];
    red[t] = p;
  }
  __syncthreads();
  if (t < 32) {
    float s = 0.f;
#pragma unroll
    for (int q = 0; q < 16; ++q) s += red[q * 32 + t];
    tm[t] = s;
  }
  __syncthreads();
  {
    float tmph = tm[hl2];
    const float* cp = c_slot + (b * 64 + kq2 * 4) * 512 + hcc * 32 + hl2;
    float s = 0.f;
#pragma unroll
    for (int l = 0; l < 4; ++l) s += ftanh(cp[l * 512] + tmph);
    red[t] = s;
  }
  __syncthreads();
  if (t < 32) {
    float s = 0.f;
#pragma unroll
    for (int q = 0; q < 16; ++q) s += red[q * 32 + t];
    ts[t] = s;
  }
  __syncthreads();
  {
    const float* vp = vsf_t + (hcc * 32) * 512 + t;
    float p = 0.f;
#pragma unroll 8
    for (int k = 0; k < 32; ++k) p += ts[k] * vp[k * 512];
    fp[blockIdx.x * 512 + t] = p;
  }
}

// ---- dominant kernel v8-fp8: bf16 inputs, 8-elem-per-thread prep ----
__global__ __launch_bounds__(512, 4) void k_score(
    const short* __restrict__ hid, const short* __restrict__ sf,
    const unsigned char* __restrict__ wbp, float* __restrict__ smat,
    float* __restrict__ oz) {
  __shared__ unsigned char As[16][2048];  // 32 KB
  __shared__ float red[8][64];
  const int i = blockIdx.x, b = blockIdx.y;
  const int t = threadIdx.x;
  if (oz && i == 1 && b < 2) oz[b * 512 + t] = 0.f;
  const int w = t >> 6, lane = t & 63;
  const int lq = lane >> 4, lm = lane & 15;

  f32x4 acc[4][4];
#pragma unroll
  for (int r = 0; r < 4; ++r)
#pragma unroll
    for (int c = 0; c < 4; ++c) acc[r][c] = (f32x4){0.f, 0.f, 0.f, 0.f};

  const short* hrow = hid + (b * 64 + i) * 512;
  const short* sfb = sf + b * 64 * 512;

  // prep: thread owns full 8-elem fragment fid = t&255, plane pair ksb = t>>8
  const int fid = t & 255, ksb = t >> 8;
  const int am = (fid >> 6) * 16 + (fid & 15);
  const int aq = (fid >> 4) & 3;
  const int aoff = fid * 8;  // byte offset of 8B dest in plane

  const short* hp0 = hrow + aq * 8;
  const short* sp0 = sfb + am * 512 + aq * 8;

  // wbp layout: [ks][w:8][lane:64][c:4][8B]; per lane 32B contiguous.
  const i64x2* gb = (const i64x2*)wbp + (w * 64 + lane) * 2;
  i64x2 nba = gb[0];      // c0,c1
  i64x2 nbb = gb[1];      // c2,c3

#pragma unroll 4
  for (int it2 = 0; it2 < 8; ++it2) {
    const int ks = it2 * 2 + ksb;
    bf16x8 hv = *(const bf16x8*)(hp0 + ks * 32);
    bf16x8 sv = *(const bf16x8*)(sp0 + ks * 32);
    unsigned pk0 = __builtin_amdgcn_cvt_pk_fp8_f32(
        ftanh(bf2f(hv[0]) + bf2f(sv[0])), ftanh(bf2f(hv[1]) + bf2f(sv[1])),
        0, false);
    pk0 = __builtin_amdgcn_cvt_pk_fp8_f32(
        ftanh(bf2f(hv[2]) + bf2f(sv[2])), ftanh(bf2f(hv[3]) + bf2f(sv[3])),
        pk0, true);
    unsigned pk1 = __builtin_amdgcn_cvt_pk_fp8_f32(
        ftanh(bf2f(hv[4]) + bf2f(sv[4])), ftanh(bf2f(hv[5]) + bf2f(sv[5])),
        0, false);
    pk1 = __builtin_amdgcn_cvt_pk_fp8_f32(
        ftanh(bf2f(hv[6]) + bf2f(sv[6])), ftanh(bf2f(hv[7]) + bf2f(sv[7])),
        pk1, true);
    uint2 pk;
    pk.x = pk0;
    pk.y = pk1;
    *(uint2*)&As[ks][aoff] = pk;
  }
  __syncthreads();

  for (int ks = 0; ks < 16; ++ks) {
    i64fr b0 = nba.x, b1 = nba.y, b2 = nbb.x, b3 = nbb.y;
    if (ks < 15) {
      nba = gb[(ks + 1) * 1024];
      nbb = gb[(ks + 1) * 1024 + 1];
    }
    i64fr af0 = *(const i64fr*)&As[ks][(0 * 64 + lane) * 8];
    i64fr af1 = *(const i64fr*)&As[ks][(1 * 64 + lane) * 8];
    i64fr af2 = *(const i64fr*)&As[ks][(2 * 64 + lane) * 8];
    i64fr af3 = *(const i64fr*)&As[ks][(3 * 64 + lane) * 8];
    acc[0][0] = __builtin_amdgcn_mfma_f32_16x16x32_fp8_fp8(af0, b0, acc[0][0], 0, 0, 0);
    acc[1][0] = __builtin_amdgcn_mfma_f32_16x16x32_fp8_fp8(af1, b0, acc[1][0], 0, 0, 0);
    acc[2][0] = __builtin_amdgcn_mfma_f32_16x16x32_fp8_fp8(af2, b0, acc[2][0], 0, 0, 0);
    acc[3][0] = __builtin_amdgcn_mfma_f32_16x16x32_fp8_fp8(af3, b0, acc[3][0], 0, 0, 0);
    acc[0][1] = __builtin_amdgcn_mfma_f32_16x16x32_fp8_fp8(af0, b1, acc[0][1], 0, 0, 0);
    acc[1][1] = __builtin_amdgcn_mfma_f32_16x16x32_fp8_fp8(af1, b1, acc[1][1], 0, 0, 0);
    acc[2][1] = __builtin_amdgcn_mfma_f32_16x16x32_fp8_fp8(af2, b1, acc[2][1], 0, 0, 0);
    acc[3][1] = __builtin_amdgcn_mfma_f32_16x16x32_fp8_fp8(af3, b1, acc[3][1], 0, 0, 0);
    acc[0][2] = __builtin_amdgcn_mfma_f32_16x16x32_fp8_fp8(af0, b2, acc[0][2], 0, 0, 0);
    acc[1][2] = __builtin_amdgcn_mfma_f32_16x16x32_fp8_fp8(af1, b2, acc[1][2], 0, 0, 0);
    acc[2][2] = __builtin_amdgcn_mfma_f32_16x16x32_fp8_fp8(af2, b2, acc[2][2], 0, 0, 0);
    acc[3][2] = __builtin_amdgcn_mfma_f32_16x16x32_fp8_fp8(af3, b2, acc[3][2], 0, 0, 0);
    acc[0][3] = __builtin_amdgcn_mfma_f32_16x16x32_fp8_fp8(af0, b3, acc[0][3], 0, 0, 0);
    acc[1][3] = __builtin_amdgcn_mfma_f32_16x16x32_fp8_fp8(af1, b3, acc[1][3], 0, 0, 0);
    acc[2][3] = __builtin_amdgcn_mfma_f32_16x16x32_fp8_fp8(af2, b3, acc[2][3], 0, 0, 0);
    acc[3][3] = __builtin_amdgcn_mfma_f32_16x16x32_fp8_fp8(af3, b3, acc[3][3], 0, 0, 0);
  }

#pragma unroll
  for (int r = 0; r < 4; ++r) {
#pragma unroll
    for (int reg = 0; reg < 4; ++reg) {
      float v = __expf(acc[r][0][reg]) + __expf(acc[r][1][reg]) +
                __expf(acc[r][2][reg]) + __expf(acc[r][3][reg]);
      v += __shfl_down(v, 8, 16);
      v += __shfl_down(v, 4, 16);
      v += __shfl_down(v, 2, 16);
      v += __shfl_down(v, 1, 16);
      if (lm == 0) red[w][r * 16 + lq * 4 + reg] = v;
    }
  }
  __syncthreads();
  if (t < 64) {
    float s = 0.f;
#pragma unroll
    for (int ww = 0; ww < 8; ++ww) s += red[ww][t];
    atomicAdd(&smat[i * 64 + t], s);
  }
}

// ---- post: k_slot (bx<256) + k_fin (bx>=256) merged (round-0 form) ----
__global__ __launch_bounds__(256) void k_post(const float* __restrict__ smat,
                                              const float* __restrict__ r_slot,
                                              const float* __restrict__ c_inte,
                                              const float* __restrict__ h,
                                              const float* __restrict__ wia_t,
                                              const float* __restrict__ wsa_t,
                                              float* __restrict__ out) {
  __shared__ float av[64], riv[64], red[256];
  const int t = threadIdx.x;
  if (blockIdx.x < 256) {
    int idx = blockIdx.x * 256 + t;  // 65536
    int ml = idx >> 6, n = idx & 63;
    const float* x1 = h + ml * 512;
    const float* x2 = r_slot + ml * 512;
    float acc = 0.f;
    for (int k = 0; k < 512; k += 4) {
      float4 x = *(const float4*)(x1 + k);
      acc += x.x * wsa_t[k * 64 + n] + x.y * wsa_t[(k + 1) * 64 + n] +
             x.z * wsa_t[(k + 2) * 64 + n] + x.w * wsa_t[(k + 3) * 64 + n];
    }
    for (int k = 0; k < 512; k += 4) {
      float4 x = *(const float4*)(x2 + k);
      acc += x.x * wsa_t[(512 + k) * 64 + n] + x.y * wsa_t[(513 + k) * 64 + n] +
             x.z * wsa_t[(514 + k) * 64 + n] + x.w * wsa_t[(515 + k) * 64 + n];
    }
    out[1024 + idx] = acc;
  } else {
    const int bb = blockIdx.x - 256;
    const int b = bb >> 3, kc = bb & 7;
    const int w = t >> 6, lane = t & 63;
    for (int r = w * 16; r < w * 16 + 16; ++r) {
      float v = smat[r * 64 + lane];
      float s = v;
      s += __shfl_xor(s, 1);
      s += __shfl_xor(s, 2);
      s += __shfl_xor(s, 4);
      s += __shfl_xor(s, 8);
      s += __shfl_xor(s, 16);
      s += __shfl_xor(s, 32);
      float d = __shfl(v, r);
      if (lane == 0) av[r] = d / s;
    }
    __syncthreads();
    {
      const int hh = kc * 64 + lane;
      float a = 0.f;
      const float* rp = r_slot + (b * 64 + w * 16) * 512 + hh;
#pragma unroll
      for (int i = 0; i < 16; ++i) a += av[w * 16 + i] * rp[i * 512];
      red[t] = a;
    }
    __syncthreads();
    if (t < 64)
      riv[t] = red[t] + red[t + 64] + red[t + 128] + red[t + 192] +
               c_inte[b * 512 + kc * 64 + t];
    __syncthreads();
    {
      const int n = lane;
      const float* hrow = h + (b * 64 + 63) * 512 + kc * 64;
      float p = 0.f;
#pragma unroll
      for (int k = w * 16; k < w * 16 + 16; ++k) {
        p += riv[k] * wia_t[(kc * 64 + k) * 64 + n];
        p += hrow[k] * wia_t[(512 + kc * 64 + k) * 64 + n];
      }
      red[t] = p;
    }
    __syncthreads();
    if (t < 64)
      atomicAdd(&out[b * 64 + t],
                red[t] + red[t + 64] + red[t + 128] + red[t + 192]);
  }
}

extern "C" void kernel_launch(void* const* d_in, const int* in_sizes, int n_in,
                              void* d_out, int out_size, void* d_ws, size_t ws_size,
                              hipStream_t stream) {
  const float* h      = (const float*)d_in[0];
  const float* c_slot = (const float*)d_in[1];
  const float* c_inte = (const float*)d_in[2];
  const float* W_SF   = (const float*)d_in[3];
  const float* V_SF   = (const float*)d_in[4];
  const float* V1_ID  = (const float*)d_in[5];
  const float* V2_w   = (const float*)d_in[6];
  const float* V2_b   = (const float*)d_in[7];
  const float* W_ID   = (const float*)d_in[8];
  const float* W_ia   = (const float*)d_in[9];
  const float* W_sa   = (const float*)d_in[10];
  float* out = (float*)d_out;

  float* ws     = (float*)d_ws;
  unsigned char* wbp = (unsigned char*)ws;
  float* fpart  = ws + 131072;
  short* v1h    = (short*)(ws + 393216);
  short* sfbuf  = (short*)(ws + 655360);
  float* r_slot = ws + 1179648;
  short* hid    = (short*)(ws + 1703936);
  float* smat   = ws + 2228224;
  float* wia_t  = ws + 2240512;
  float* wsa_t  = ws + 2306048;
  float* wsf_t  = ws + 2371584;
  float* vsf_t  = ws + 2633728;

  k_lin1<<<dim3(64, 17), 256, 0, stream>>>(h, V2_w, V2_b, sfbuf,
                                           W_ID, V1_ID, W_ia, W_sa, W_SF, V_SF,
                                           c_inte, c_slot,
                                           wbp, v1h,
                                           wia_t, wsa_t, wsf_t, vsf_t, fpart);

  for (int it = 0; it < 3; ++it) {
    if (it > 0)
      k_mid<<<256, 512, 0, stream>>>(smat, r_slot, c_inte, c_slot,
                                     wsf_t, vsf_t, fpart);
    k_lin<<<dim3(64, 8), 256, 0, stream>>>(c_slot, fpart, it == 0 ? 8 : 16,
                                           v1h, hid, r_slot, smat);
    k_score<<<dim3(64, 16), 512, 0, stream>>>(hid, sfbuf, wbp, smat,
                                              it == 2 ? out : nullptr);
  }

  k_post<<<384, 256, 0, stream>>>(smat, r_slot, c_inte, h, wia_t, wsa_t, out);
}